// Round 9
// baseline (237.053 us; speedup 1.0000x reference)
//
#include <hip/hip_runtime.h>
#include <hip/hip_bf16.h>

#define N_ENT 50000
#define N_EDG 600000
#define CH 128
#define LEAKY 0.01f
#define NB_SCAN 49
#define NSTRIP 3125       // 50000 / 16
#define GEMM_BLOCKS 1042  // 3 strips per block (grid-stride)
#define AGG_BLOCKS 6250   // 8 rows per block, exact

typedef __attribute__((ext_vector_type(8))) short bf16x8;
typedef __attribute__((ext_vector_type(4))) float f32x4;

__device__ inline unsigned short f2bf(float x) {
    return __builtin_bit_cast(unsigned short, __float2bfloat16(x));
}
__device__ inline float bflo(unsigned u) { return __builtin_bit_cast(float, u << 16); }
__device__ inline float bfhi(unsigned u) { return __builtin_bit_cast(float, u & 0xFFFF0000u); }

// ---------------- CSR build step 1: in-degree counts ------------------------
__global__ __launch_bounds__(256) void count_kernel(const int* __restrict__ head,
                                                    int* __restrict__ counts) {
    int e = blockIdx.x * 256 + threadIdx.x;
    if (e < N_EDG) atomicAdd(&counts[head[e]], 1);
}

// ---------------- CSR step 2a: per-1024-chunk exclusive scan ----------------
__global__ __launch_bounds__(256) void scan_block(const int* __restrict__ counts,
                                                  int* __restrict__ offs,
                                                  int* __restrict__ bsum) {
    __shared__ int s[256];
    int t = threadIdx.x;
    int base = blockIdx.x * 1024 + t * 4;
    int v[4];
#pragma unroll
    for (int i = 0; i < 4; ++i) {
        int idx = base + i;
        v[i] = (idx < N_ENT) ? counts[idx] : 0;
    }
    int tot = v[0] + v[1] + v[2] + v[3];
    s[t] = tot;
    for (int off = 1; off < 256; off <<= 1) {
        __syncthreads();
        int x = (t >= off) ? s[t - off] : 0;
        __syncthreads();
        s[t] += x;
    }
    int run = s[t] - tot;
#pragma unroll
    for (int i = 0; i < 4; ++i) {
        if (base + i < N_ENT) offs[base + i] = run;
        run += v[i];
    }
    if (t == 255) bsum[blockIdx.x] = s[255];
}

// ---------------- CSR step 2b: scan the 49 chunk totals ----------------------
__global__ __launch_bounds__(64) void scan_tops(int* __restrict__ bsum) {
    int lane = threadIdx.x;
    int v = (lane < NB_SCAN) ? bsum[lane] : 0;
    int orig = v;
#pragma unroll
    for (int off = 1; off < 64; off <<= 1) {
        int x = __shfl_up(v, off);
        if (lane >= off) v += x;
    }
    if (lane < NB_SCAN) bsum[lane] = v - orig;
}

// ---------------- CSR step 2c: add chunk base, init cursors ------------------
__global__ __launch_bounds__(256) void add_base(int* __restrict__ offs,
                                                int* __restrict__ cursors,
                                                const int* __restrict__ bsum) {
    int t = threadIdx.x;
    int base = blockIdx.x * 1024 + t * 4;
    int b = bsum[blockIdx.x];
#pragma unroll
    for (int i = 0; i < 4; ++i) {
        int idx = base + i;
        if (idx < N_ENT) {
            int o = offs[idx] + b;
            offs[idx] = o;
            cursors[idx] = o;
        }
    }
    if (blockIdx.x == 0 && t == 0) offs[N_ENT] = N_EDG;
}

// ---------------- CSR step 3: fill packed edge payloads ----------------------
__global__ __launch_bounds__(256) void fill_kernel(const int* __restrict__ head,
                                                   const int* __restrict__ tail,
                                                   const int* __restrict__ etype,
                                                   int* __restrict__ cursors,
                                                   int* __restrict__ packed) {
    int e = blockIdx.x * 256 + threadIdx.x;
    if (e >= N_EDG) return;
    int h = head[e];
    int pos = atomicAdd(&cursors[h], 1);
    packed[pos] = tail[e] | (etype[e] << 20);
}

// ---------------- one-time conversions: x->bf16, weights->bf16, weight copy --
__global__ __launch_bounds__(256) void prep_cvt(const float* __restrict__ emb,
                                                const float* __restrict__ W1,
                                                const float* __restrict__ W2,
                                                const float* __restrict__ wsrc,
                                                unsigned short* __restrict__ xh,
                                                unsigned short* __restrict__ w1bf,
                                                unsigned short* __restrict__ w2bf,
                                                float* __restrict__ wout) {
    long long gid = (long long)blockIdx.x * 256 + threadIdx.x;  // float4 units
    const long long n_x = (long long)N_ENT * CH / 4;   // 1,600,000
    const long long n_w1 = 2 * CH * CH / 4;            // 8,192
    const long long n_w2 = 2 * CH * 2 * CH / 4;        // 16,384
    // total with copyw: 1,625,600 = 6350 * 256 exactly
    if (gid < n_x) {
        long long k = gid * 4;
        float4 v = *(const float4*)&emb[k];
        ushort4 o;
        o.x = f2bf(v.x); o.y = f2bf(v.y); o.z = f2bf(v.z); o.w = f2bf(v.w);
        *(ushort4*)&xh[k] = o;
    } else if (gid < n_x + n_w1) {
        long long k = (gid - n_x) * 4;
        float4 v = *(const float4*)&W1[k];
        ushort4 o;
        o.x = f2bf(v.x); o.y = f2bf(v.y); o.z = f2bf(v.z); o.w = f2bf(v.w);
        *(ushort4*)&w1bf[k] = o;
    } else if (gid < n_x + n_w1 + n_w2) {
        long long k = (gid - n_x - n_w1) * 4;
        float4 v = *(const float4*)&W2[k];
        ushort4 o;
        o.x = f2bf(v.x); o.y = f2bf(v.y); o.z = f2bf(v.z); o.w = f2bf(v.w);
        *(ushort4*)&w2bf[k] = o;
    } else {
        long long k = (gid - n_x - n_w1 - n_w2) * 4;  // < 1024*4
        *(float4*)&wout[k] = *(const float4*)&wsrc[k];
    }
}

// ---------------- aggregate + mean + L2-normalize -----------------------------
// One wave per head row; lane owns channels [2*lane, 2*lane+1].
// All edge metadata scalarized (readfirstlane -> s_load; gather = SGPR base +
// constant voffset -> zero per-edge VALU address math). 4-deep gather unroll.
__global__ __launch_bounds__(512) void agg_kernel(
    const unsigned short* __restrict__ xin, const int* __restrict__ offs,
    const int* __restrict__ packed, const float* __restrict__ rw,
    unsigned short* __restrict__ aggb) {
    __shared__ float ws_[32 * CH];  // stride 128; rows accessed uniformly -> no conflicts
    int tid = threadIdx.x;
    {
        int base = tid * 8;  // 4096 floats / 512 threads
        *(float4*)&ws_[base] = *(const float4*)&rw[base];
        *(float4*)&ws_[base + 4] = *(const float4*)&rw[base + 4];
    }
    __syncthreads();

    const int w = tid >> 6;
    const int lane = tid & 63;
    const int c2 = lane * 2;
    const int row = blockIdx.x * 8 + w;
    const int beg = __builtin_amdgcn_readfirstlane(offs[row]);
    const int end = __builtin_amdgcn_readfirstlane(offs[row + 1]);

    float2 a0 = {0.f, 0.f}, a1 = {0.f, 0.f}, a2 = {0.f, 0.f}, a3 = {0.f, 0.f};
    int i = beg;
    for (; i + 4 <= end; i += 4) {
        int p0 = __builtin_amdgcn_readfirstlane(packed[i]);
        int p1 = __builtin_amdgcn_readfirstlane(packed[i + 1]);
        int p2 = __builtin_amdgcn_readfirstlane(packed[i + 2]);
        int p3 = __builtin_amdgcn_readfirstlane(packed[i + 3]);
        unsigned v0 = *(const unsigned*)&xin[(long long)(p0 & 0xFFFFF) * CH + c2];
        unsigned v1 = *(const unsigned*)&xin[(long long)(p1 & 0xFFFFF) * CH + c2];
        unsigned v2 = *(const unsigned*)&xin[(long long)(p2 & 0xFFFFF) * CH + c2];
        unsigned v3 = *(const unsigned*)&xin[(long long)(p3 & 0xFFFFF) * CH + c2];
        float2 w0 = *(const float2*)&ws_[((p0 >> 20) << 7) + c2];
        float2 w1 = *(const float2*)&ws_[((p1 >> 20) << 7) + c2];
        float2 w2 = *(const float2*)&ws_[((p2 >> 20) << 7) + c2];
        float2 w3 = *(const float2*)&ws_[((p3 >> 20) << 7) + c2];
        a0.x = fmaf(bflo(v0), w0.x, a0.x); a0.y = fmaf(bfhi(v0), w0.y, a0.y);
        a1.x = fmaf(bflo(v1), w1.x, a1.x); a1.y = fmaf(bfhi(v1), w1.y, a1.y);
        a2.x = fmaf(bflo(v2), w2.x, a2.x); a2.y = fmaf(bfhi(v2), w2.y, a2.y);
        a3.x = fmaf(bflo(v3), w3.x, a3.x); a3.y = fmaf(bfhi(v3), w3.y, a3.y);
    }
    for (; i < end; ++i) {
        int p = __builtin_amdgcn_readfirstlane(packed[i]);
        unsigned v = *(const unsigned*)&xin[(long long)(p & 0xFFFFF) * CH + c2];
        float2 wv = *(const float2*)&ws_[((p >> 20) << 7) + c2];
        a0.x = fmaf(bflo(v), wv.x, a0.x);
        a0.y = fmaf(bfhi(v), wv.y, a0.y);
    }

    float2 acc = {a0.x + a1.x + a2.x + a3.x, a0.y + a1.y + a2.y + a3.y};
    float d = fmaxf((float)(end - beg), 1.f);
    acc.x /= d;
    acc.y /= d;
    float ss = acc.x * acc.x + acc.y * acc.y;
#pragma unroll
    for (int off = 32; off >= 1; off >>= 1) ss += __shfl_xor(ss, off);
    float inv = 1.0f / fmaxf(sqrtf(ss), 1e-12f);
    ushort2 o;
    o.x = f2bf(acc.x * inv);
    o.y = f2bf(acc.y * inv);
    *(ushort2*)&aggb[(long long)row * CH + c2] = o;
}

// ---------------- MFMA dual-GEMM + leaky + add -------------------------------
// out = leaky((x+agg)@W1^T + b1) + leaky(x@W2a^T + agg@W2b^T + b2)
// 512 thr / 8 waves; wave w owns cols [16w,16w+16): 12 B-frags = 48 VGPR
// register-resident. No LDS, no barriers (ping-pong buffers, never in-place).
__global__ __launch_bounds__(512) void gemm_kernel(
    const unsigned short* __restrict__ xin, const unsigned short* __restrict__ aggb,
    const unsigned short* __restrict__ w1bf, const unsigned short* __restrict__ w2bf,
    const float* __restrict__ b1, const float* __restrict__ b2,
    unsigned short* __restrict__ xout, float* __restrict__ outf) {
    const int tid = threadIdx.x;
    const int w = tid >> 6;
    const int lane = tid & 63;
    const int l16 = lane & 15;
    const int khi = (lane >> 4) * 8;
    const int j = w * 16 + l16;

    bf16x8 bW1[4], bWa[4], bWb[4];
    const float bb1 = b1[j];
    const float bb2 = b2[j];
#pragma unroll
    for (int kst = 0; kst < 4; ++kst) {
        int kk = kst * 32 + khi;
        bW1[kst] = *(const bf16x8*)&w1bf[j * CH + kk];
        bWa[kst] = *(const bf16x8*)&w2bf[j * 2 * CH + kk];
        bWb[kst] = *(const bf16x8*)&w2bf[j * 2 * CH + CH + kk];
    }

    for (int strip = blockIdx.x; strip < NSTRIP; strip += GEMM_BLOCKS) {
        const int row0 = strip * 16;
        long long abase = (long long)(row0 + l16) * CH + khi;
        f32x4 acc1 = {0.f, 0.f, 0.f, 0.f};
        f32x4 acc2 = {0.f, 0.f, 0.f, 0.f};
#pragma unroll
        for (int kst = 0; kst < 4; ++kst) {
            bf16x8 rh = *(const bf16x8*)&xin[abase + kst * 32];
            bf16x8 av = *(const bf16x8*)&aggb[abase + kst * 32];
            acc1 = __builtin_amdgcn_mfma_f32_16x16x32_bf16(rh, bW1[kst], acc1, 0, 0, 0);
            acc1 = __builtin_amdgcn_mfma_f32_16x16x32_bf16(av, bW1[kst], acc1, 0, 0, 0);
            acc2 = __builtin_amdgcn_mfma_f32_16x16x32_bf16(rh, bWa[kst], acc2, 0, 0, 0);
            acc2 = __builtin_amdgcn_mfma_f32_16x16x32_bf16(av, bWb[kst], acc2, 0, 0, 0);
        }
#pragma unroll
        for (int r = 0; r < 4; ++r) {
            long long row = row0 + (lane >> 4) * 4 + r;
            float e1 = acc1[r] + bb1;
            e1 = e1 >= 0.f ? e1 : LEAKY * e1;
            float e2 = acc2[r] + bb2;
            e2 = e2 >= 0.f ? e2 : LEAKY * e2;
            float val = e1 + e2;
            if (outf)
                outf[row * CH + j] = val;
            else
                xout[row * CH + j] = f2bf(val);
        }
    }
}

extern "C" void kernel_launch(void* const* d_in, const int* in_sizes, int n_in,
                              void* d_out, int out_size, void* d_ws, size_t ws_size,
                              hipStream_t stream) {
    const float* emb = (const float*)d_in[0];
    const int* eidx = (const int*)d_in[1];   // int inputs arrive as int32
    const int* etype = (const int*)d_in[2];
    const float* weight = (const float*)d_in[3];
    const float* W1w = (const float*)d_in[4];
    const float* W1b = (const float*)d_in[5];
    const float* W2w = (const float*)d_in[6];
    const float* W2b = (const float*)d_in[7];

    float* out = (float*)d_out;
    float* wout = out + (size_t)N_ENT * CH;   // [32][CH]

    // workspace layout (~41.6 MB; r5/r6 proved >=41.7 MB available)
    char* ws = (char*)d_ws;
    unsigned short* xh = (unsigned short*)ws;    ws += (size_t)N_ENT * CH * 2;  // 12.8 MB
    unsigned short* xh2 = (unsigned short*)ws;   ws += (size_t)N_ENT * CH * 2;  // 12.8 MB
    unsigned short* aggb = (unsigned short*)ws;  ws += (size_t)N_ENT * CH * 2;  // 12.8 MB
    unsigned short* w1bf = (unsigned short*)ws;  ws += 2 * CH * CH * 2;         // 64 KB
    unsigned short* w2bf = (unsigned short*)ws;  ws += 2 * CH * 2 * CH * 2;     // 128 KB
    int* packed = (int*)ws;                      ws += (size_t)N_EDG * 4;       // 2.4 MB
    int* offs = (int*)ws;                        ws += (size_t)(N_ENT + 1) * 4;
    int* cursors = (int*)ws;                     ws += (size_t)N_ENT * 4;
    int* counts = (int*)ws;                      ws += (size_t)N_ENT * 4;
    int* bsum = (int*)ws;                        ws += 64 * 4;

    const int* head = eidx;
    const int* tail = eidx + N_EDG;

    // ---- one-time prep: CSR + bf16 operand planes (+ weight output copy) ----
    hipMemsetAsync(counts, 0, N_ENT * sizeof(int), stream);
    count_kernel<<<(N_EDG + 255) / 256, 256, 0, stream>>>(head, counts);
    scan_block<<<NB_SCAN, 256, 0, stream>>>(counts, offs, bsum);
    scan_tops<<<1, 64, 0, stream>>>(bsum);
    add_base<<<NB_SCAN, 256, 0, stream>>>(offs, cursors, bsum);
    fill_kernel<<<(N_EDG + 255) / 256, 256, 0, stream>>>(head, tail, etype, cursors, packed);
    prep_cvt<<<6350, 256, 0, stream>>>(emb, W1w, W2w, weight, xh, w1bf, w2bf, wout);

    // ---- 2 hops, ping-pong: xh -> (aggb) -> xh2 -> (aggb) -> d_out ----
    agg_kernel<<<AGG_BLOCKS, 512, 0, stream>>>(xh, offs, packed, weight, aggb);
    gemm_kernel<<<GEMM_BLOCKS, 512, 0, stream>>>(
        xh, aggb, w1bf, w2bf, W1b, W2b, xh2, (float*)nullptr);
    agg_kernel<<<AGG_BLOCKS, 512, 0, stream>>>(xh2, offs, packed, weight, aggb);
    gemm_kernel<<<GEMM_BLOCKS, 512, 0, stream>>>(
        xh2, aggb, w1bf + CH * CH, w2bf + CH * 2 * CH,
        W1b + CH, W2b + CH, (unsigned short*)nullptr, out);
}

// Round 10
// 230.098 us; speedup vs baseline: 1.0302x; 1.0302x over previous
//
#include <hip/hip_runtime.h>
#include <hip/hip_bf16.h>

#define N_ENT 50000
#define N_EDG 600000
#define CH 128
#define LEAKY 0.01f
#define NB_SCAN 49
#define NSTRIP 3125       // 50000 / 16
#define GEMM_BLOCKS 1042  // 3 strips per block (grid-stride)
#define AGG_BLOCKS 6250   // 8 rows per block, exact
#define FILL_CHUNK 4800   // 600000 = 125 * 4800
#define HEADS_PER_GRP 6250  // 50000 / 8

typedef __attribute__((ext_vector_type(8))) short bf16x8;
typedef __attribute__((ext_vector_type(4))) float f32x4;

__device__ inline unsigned short f2bf(float x) {
    return __builtin_bit_cast(unsigned short, __float2bfloat16(x));
}
__device__ inline float bflo(unsigned u) { return __builtin_bit_cast(float, u << 16); }
__device__ inline float bfhi(unsigned u) { return __builtin_bit_cast(float, u & 0xFFFF0000u); }

// ---------------- CSR build step 1: in-degree counts ------------------------
__global__ __launch_bounds__(256) void count_kernel(const int* __restrict__ head,
                                                    int* __restrict__ counts) {
    int e = blockIdx.x * 256 + threadIdx.x;
    if (e < N_EDG) atomicAdd(&counts[head[e]], 1);
}

// ---------------- CSR step 2a: per-1024-chunk exclusive scan ----------------
__global__ __launch_bounds__(256) void scan_block(const int* __restrict__ counts,
                                                  int* __restrict__ offs,
                                                  int* __restrict__ bsum) {
    __shared__ int s[256];
    int t = threadIdx.x;
    int base = blockIdx.x * 1024 + t * 4;
    int v[4];
#pragma unroll
    for (int i = 0; i < 4; ++i) {
        int idx = base + i;
        v[i] = (idx < N_ENT) ? counts[idx] : 0;
    }
    int tot = v[0] + v[1] + v[2] + v[3];
    s[t] = tot;
    for (int off = 1; off < 256; off <<= 1) {
        __syncthreads();
        int x = (t >= off) ? s[t - off] : 0;
        __syncthreads();
        s[t] += x;
    }
    int run = s[t] - tot;
#pragma unroll
    for (int i = 0; i < 4; ++i) {
        if (base + i < N_ENT) offs[base + i] = run;
        run += v[i];
    }
    if (t == 255) bsum[blockIdx.x] = s[255];
}

// ---------------- CSR step 2b: scan the 49 chunk totals ----------------------
__global__ __launch_bounds__(64) void scan_tops(int* __restrict__ bsum) {
    int lane = threadIdx.x;
    int v = (lane < NB_SCAN) ? bsum[lane] : 0;
    int orig = v;
#pragma unroll
    for (int off = 1; off < 64; off <<= 1) {
        int x = __shfl_up(v, off);
        if (lane >= off) v += x;
    }
    if (lane < NB_SCAN) bsum[lane] = v - orig;
}

// ---------------- CSR step 2c: add chunk base, init cursors ------------------
__global__ __launch_bounds__(256) void add_base(int* __restrict__ offs,
                                                int* __restrict__ cursors,
                                                const int* __restrict__ bsum) {
    int t = threadIdx.x;
    int base = blockIdx.x * 1024 + t * 4;
    int b = bsum[blockIdx.x];
#pragma unroll
    for (int i = 0; i < 4; ++i) {
        int idx = base + i;
        if (idx < N_ENT) {
            int o = offs[idx] + b;
            offs[idx] = o;
            cursors[idx] = o;
        }
    }
    if (blockIdx.x == 0 && t == 0) offs[N_ENT] = N_EDG;
}

// ---------------- CSR step 3: fill packed edge payloads (XCD-partitioned) ----
// Group g = blocks with blockIdx%8==g (round-robin blockIdx->XCD): owns heads
// [g*6250,(g+1)*6250). Each group scans all edges (8x reads, L3-cheap) but
// writes only its 1/8 of packed -> each packed line dirtied by ONE XCD's L2
// -> single writeback (fixes the 16x write amplification seen in r9).
__global__ __launch_bounds__(256) void fill_kernel(const int* __restrict__ head,
                                                   const int* __restrict__ tail,
                                                   const int* __restrict__ etype,
                                                   int* __restrict__ cursors,
                                                   int* __restrict__ packed) {
    int g = blockIdx.x & 7;
    int c = blockIdx.x >> 3;  // 0..124
    int hlo = g * HEADS_PER_GRP;
    int hhi = hlo + HEADS_PER_GRP;
    int base = c * FILL_CHUNK;
    for (int t = threadIdx.x; t < FILL_CHUNK; t += 256) {
        int e = base + t;
        int h = head[e];
        if (h >= hlo && h < hhi) {
            int pos = atomicAdd(&cursors[h], 1);
            packed[pos] = tail[e] | (etype[e] << 20);
        }
    }
}

// ---------------- one-time conversions: x->bf16, weights->bf16, weight copy --
__global__ __launch_bounds__(256) void prep_cvt(const float* __restrict__ emb,
                                                const float* __restrict__ W1,
                                                const float* __restrict__ W2,
                                                const float* __restrict__ wsrc,
                                                unsigned short* __restrict__ xh,
                                                unsigned short* __restrict__ w1bf,
                                                unsigned short* __restrict__ w2bf,
                                                float* __restrict__ wout) {
    long long gid = (long long)blockIdx.x * 256 + threadIdx.x;  // float4 units
    const long long n_x = (long long)N_ENT * CH / 4;   // 1,600,000
    const long long n_w1 = 2 * CH * CH / 4;            // 8,192
    const long long n_w2 = 2 * CH * 2 * CH / 4;        // 16,384
    // total with copyw: 1,625,600 = 6350 * 256 exactly
    if (gid < n_x) {
        long long k = gid * 4;
        float4 v = *(const float4*)&emb[k];
        ushort4 o;
        o.x = f2bf(v.x); o.y = f2bf(v.y); o.z = f2bf(v.z); o.w = f2bf(v.w);
        *(ushort4*)&xh[k] = o;
    } else if (gid < n_x + n_w1) {
        long long k = (gid - n_x) * 4;
        float4 v = *(const float4*)&W1[k];
        ushort4 o;
        o.x = f2bf(v.x); o.y = f2bf(v.y); o.z = f2bf(v.z); o.w = f2bf(v.w);
        *(ushort4*)&w1bf[k] = o;
    } else if (gid < n_x + n_w1 + n_w2) {
        long long k = (gid - n_x - n_w1) * 4;
        float4 v = *(const float4*)&W2[k];
        ushort4 o;
        o.x = f2bf(v.x); o.y = f2bf(v.y); o.z = f2bf(v.z); o.w = f2bf(v.w);
        *(ushort4*)&w2bf[k] = o;
    } else {
        long long k = (gid - n_x - n_w1 - n_w2) * 4;  // < 1024*4
        *(float4*)&wout[k] = *(const float4*)&wsrc[k];
    }
}

// ---------------- aggregate + mean + L2-normalize -----------------------------
// One wave per head row; lane owns channels [2*lane, 2*lane+1].
// Edge metadata scalarized (readfirstlane); gather = base + const voffset.
__global__ __launch_bounds__(512) void agg_kernel(
    const unsigned short* __restrict__ xin, const int* __restrict__ offs,
    const int* __restrict__ packed, const float* __restrict__ rw,
    unsigned short* __restrict__ aggb) {
    __shared__ float ws_[32 * CH];  // rows accessed wave-uniformly -> no conflicts
    int tid = threadIdx.x;
    {
        int base = tid * 8;  // 4096 floats / 512 threads
        *(float4*)&ws_[base] = *(const float4*)&rw[base];
        *(float4*)&ws_[base + 4] = *(const float4*)&rw[base + 4];
    }
    __syncthreads();

    const int w = tid >> 6;
    const int lane = tid & 63;
    const int c2 = lane * 2;
    const int row = blockIdx.x * 8 + w;
    const int beg = __builtin_amdgcn_readfirstlane(offs[row]);
    const int end = __builtin_amdgcn_readfirstlane(offs[row + 1]);

    float2 a0 = {0.f, 0.f}, a1 = {0.f, 0.f}, a2 = {0.f, 0.f}, a3 = {0.f, 0.f};
    int i = beg;
    for (; i + 4 <= end; i += 4) {
        int p0 = __builtin_amdgcn_readfirstlane(packed[i]);
        int p1 = __builtin_amdgcn_readfirstlane(packed[i + 1]);
        int p2 = __builtin_amdgcn_readfirstlane(packed[i + 2]);
        int p3 = __builtin_amdgcn_readfirstlane(packed[i + 3]);
        unsigned v0 = *(const unsigned*)&xin[(long long)(p0 & 0xFFFFF) * CH + c2];
        unsigned v1 = *(const unsigned*)&xin[(long long)(p1 & 0xFFFFF) * CH + c2];
        unsigned v2 = *(const unsigned*)&xin[(long long)(p2 & 0xFFFFF) * CH + c2];
        unsigned v3 = *(const unsigned*)&xin[(long long)(p3 & 0xFFFFF) * CH + c2];
        float2 w0 = *(const float2*)&ws_[((p0 >> 20) << 7) + c2];
        float2 w1 = *(const float2*)&ws_[((p1 >> 20) << 7) + c2];
        float2 w2 = *(const float2*)&ws_[((p2 >> 20) << 7) + c2];
        float2 w3 = *(const float2*)&ws_[((p3 >> 20) << 7) + c2];
        a0.x = fmaf(bflo(v0), w0.x, a0.x); a0.y = fmaf(bfhi(v0), w0.y, a0.y);
        a1.x = fmaf(bflo(v1), w1.x, a1.x); a1.y = fmaf(bfhi(v1), w1.y, a1.y);
        a2.x = fmaf(bflo(v2), w2.x, a2.x); a2.y = fmaf(bfhi(v2), w2.y, a2.y);
        a3.x = fmaf(bflo(v3), w3.x, a3.x); a3.y = fmaf(bfhi(v3), w3.y, a3.y);
    }
    for (; i < end; ++i) {
        int p = __builtin_amdgcn_readfirstlane(packed[i]);
        unsigned v = *(const unsigned*)&xin[(long long)(p & 0xFFFFF) * CH + c2];
        float2 wv = *(const float2*)&ws_[((p >> 20) << 7) + c2];
        a0.x = fmaf(bflo(v), wv.x, a0.x);
        a0.y = fmaf(bfhi(v), wv.y, a0.y);
    }

    float2 acc = {a0.x + a1.x + a2.x + a3.x, a0.y + a1.y + a2.y + a3.y};
    float d = fmaxf((float)(end - beg), 1.f);
    acc.x /= d;
    acc.y /= d;
    float ss = acc.x * acc.x + acc.y * acc.y;
#pragma unroll
    for (int off = 32; off >= 1; off >>= 1) ss += __shfl_xor(ss, off);
    float inv = 1.0f / fmaxf(sqrtf(ss), 1e-12f);
    ushort2 o;
    o.x = f2bf(acc.x * inv);
    o.y = f2bf(acc.y * inv);
    *(ushort2*)&aggb[(long long)row * CH + c2] = o;
}

// ---------------- MFMA dual-GEMM + leaky + add -------------------------------
// out = leaky((x+agg)@W1^T + b1) + leaky(x@W2a^T + agg@W2b^T + b2)
// 512 thr / 8 waves; wave w owns cols [16w,16w+16). B-frags loaded once and
// PINNED via asm (r7/r9 showed the compiler otherwise rematerializes the
// loads per strip, making each strip a serial L2-latency chain).
__global__ __launch_bounds__(512) void gemm_kernel(
    const unsigned short* __restrict__ xin, const unsigned short* __restrict__ aggb,
    const unsigned short* __restrict__ w1bf, const unsigned short* __restrict__ w2bf,
    const float* __restrict__ b1, const float* __restrict__ b2,
    unsigned short* __restrict__ xout, float* __restrict__ outf) {
    const int tid = threadIdx.x;
    const int w = tid >> 6;
    const int lane = tid & 63;
    const int l16 = lane & 15;
    const int khi = (lane >> 4) * 8;
    const int j = w * 16 + l16;

    bf16x8 bW1[4], bWa[4], bWb[4];
    const float bb1 = b1[j];
    const float bb2 = b2[j];
#pragma unroll
    for (int kst = 0; kst < 4; ++kst) {
        int kk = kst * 32 + khi;
        bW1[kst] = *(const bf16x8*)&w1bf[j * CH + kk];
        bWa[kst] = *(const bf16x8*)&w2bf[j * 2 * CH + kk];
        bWb[kst] = *(const bf16x8*)&w2bf[j * 2 * CH + CH + kk];
    }
    // pin: values become opaque -> compiler cannot rematerialize the loads
    asm volatile("" : "+v"(bW1[0]), "+v"(bW1[1]), "+v"(bW1[2]), "+v"(bW1[3]),
                      "+v"(bWa[0]), "+v"(bWa[1]), "+v"(bWa[2]), "+v"(bWa[3]),
                      "+v"(bWb[0]), "+v"(bWb[1]), "+v"(bWb[2]), "+v"(bWb[3]));

    for (int strip = blockIdx.x; strip < NSTRIP; strip += GEMM_BLOCKS) {
        const int row0 = strip * 16;
        long long abase = (long long)(row0 + l16) * CH + khi;
        f32x4 acc1 = {0.f, 0.f, 0.f, 0.f};
        f32x4 acc2 = {0.f, 0.f, 0.f, 0.f};
#pragma unroll
        for (int kst = 0; kst < 4; ++kst) {
            bf16x8 rh = *(const bf16x8*)&xin[abase + kst * 32];
            bf16x8 av = *(const bf16x8*)&aggb[abase + kst * 32];
            acc1 = __builtin_amdgcn_mfma_f32_16x16x32_bf16(rh, bW1[kst], acc1, 0, 0, 0);
            acc1 = __builtin_amdgcn_mfma_f32_16x16x32_bf16(av, bW1[kst], acc1, 0, 0, 0);
            acc2 = __builtin_amdgcn_mfma_f32_16x16x32_bf16(rh, bWa[kst], acc2, 0, 0, 0);
            acc2 = __builtin_amdgcn_mfma_f32_16x16x32_bf16(av, bWb[kst], acc2, 0, 0, 0);
        }
#pragma unroll
        for (int r = 0; r < 4; ++r) {
            long long row = row0 + (lane >> 4) * 4 + r;
            float e1 = acc1[r] + bb1;
            e1 = e1 >= 0.f ? e1 : LEAKY * e1;
            float e2 = acc2[r] + bb2;
            e2 = e2 >= 0.f ? e2 : LEAKY * e2;
            float val = e1 + e2;
            if (outf)
                outf[row * CH + j] = val;
            else
                xout[row * CH + j] = f2bf(val);
        }
    }
}

extern "C" void kernel_launch(void* const* d_in, const int* in_sizes, int n_in,
                              void* d_out, int out_size, void* d_ws, size_t ws_size,
                              hipStream_t stream) {
    const float* emb = (const float*)d_in[0];
    const int* eidx = (const int*)d_in[1];   // int inputs arrive as int32
    const int* etype = (const int*)d_in[2];
    const float* weight = (const float*)d_in[3];
    const float* W1w = (const float*)d_in[4];
    const float* W1b = (const float*)d_in[5];
    const float* W2w = (const float*)d_in[6];
    const float* W2b = (const float*)d_in[7];

    float* out = (float*)d_out;
    float* wout = out + (size_t)N_ENT * CH;   // [32][CH]

    // workspace layout (~41.6 MB; proven fits)
    char* ws = (char*)d_ws;
    unsigned short* xh = (unsigned short*)ws;    ws += (size_t)N_ENT * CH * 2;  // 12.8 MB
    unsigned short* xh2 = (unsigned short*)ws;   ws += (size_t)N_ENT * CH * 2;  // 12.8 MB
    unsigned short* aggb = (unsigned short*)ws;  ws += (size_t)N_ENT * CH * 2;  // 12.8 MB
    unsigned short* w1bf = (unsigned short*)ws;  ws += 2 * CH * CH * 2;         // 64 KB
    unsigned short* w2bf = (unsigned short*)ws;  ws += 2 * CH * 2 * CH * 2;     // 128 KB
    int* packed = (int*)ws;                      ws += (size_t)N_EDG * 4;       // 2.4 MB
    int* offs = (int*)ws;                        ws += (size_t)(N_ENT + 1) * 4;
    int* cursors = (int*)ws;                     ws += (size_t)N_ENT * 4;
    int* counts = (int*)ws;                      ws += (size_t)N_ENT * 4;
    int* bsum = (int*)ws;                        ws += 64 * 4;

    const int* head = eidx;
    const int* tail = eidx + N_EDG;

    // ---- one-time prep: CSR + bf16 operand planes (+ weight output copy) ----
    hipMemsetAsync(counts, 0, N_ENT * sizeof(int), stream);
    count_kernel<<<(N_EDG + 255) / 256, 256, 0, stream>>>(head, counts);
    scan_block<<<NB_SCAN, 256, 0, stream>>>(counts, offs, bsum);
    scan_tops<<<1, 64, 0, stream>>>(bsum);
    add_base<<<NB_SCAN, 256, 0, stream>>>(offs, cursors, bsum);
    fill_kernel<<<1000, 256, 0, stream>>>(head, tail, etype, cursors, packed);
    prep_cvt<<<6350, 256, 0, stream>>>(emb, W1w, W2w, weight, xh, w1bf, w2bf, wout);

    // ---- 2 hops, ping-pong: xh -> (aggb) -> xh2 -> (aggb) -> d_out ----
    agg_kernel<<<AGG_BLOCKS, 512, 0, stream>>>(xh, offs, packed, weight, aggb);
    gemm_kernel<<<GEMM_BLOCKS, 512, 0, stream>>>(
        xh, aggb, w1bf, w2bf, W1b, W2b, xh2, (float*)nullptr);
    agg_kernel<<<AGG_BLOCKS, 512, 0, stream>>>(xh2, offs, packed, weight, aggb);
    gemm_kernel<<<GEMM_BLOCKS, 512, 0, stream>>>(
        xh2, aggb, w1bf + CH * CH, w2bf + CH * 2 * CH,
        W1b + CH, W2b + CH, (unsigned short*)nullptr, out);
}

// Round 11
// 222.003 us; speedup vs baseline: 1.0678x; 1.0365x over previous
//
#include <hip/hip_runtime.h>
#include <hip/hip_bf16.h>

#define N_ENT 50000
#define N_EDG 600000
#define CH 128
#define LEAKY 0.01f
#define NB_SCAN 49
#define NSTRIP 3125       // 50000 / 16
#define AGG_BLOCKS 6250   // 8 rows per block, exact
#define FILL_CHUNK 4800   // 600000 = 125 * 4800
#define HEADS_PER_GRP 6250  // 50000 / 8

typedef __attribute__((ext_vector_type(8))) short bf16x8;
typedef __attribute__((ext_vector_type(4))) float f32x4;

__device__ inline unsigned short f2bf(float x) {
    return __builtin_bit_cast(unsigned short, __float2bfloat16(x));
}
__device__ inline float bflo(unsigned u) { return __builtin_bit_cast(float, u << 16); }
__device__ inline float bfhi(unsigned u) { return __builtin_bit_cast(float, u & 0xFFFF0000u); }

// ---------------- CSR build step 1: in-degree counts ------------------------
__global__ __launch_bounds__(256) void count_kernel(const int* __restrict__ head,
                                                    int* __restrict__ counts) {
    int e = blockIdx.x * 256 + threadIdx.x;
    if (e < N_EDG) atomicAdd(&counts[head[e]], 1);
}

// ---------------- CSR step 2a: per-1024-chunk exclusive scan ----------------
__global__ __launch_bounds__(256) void scan_block(const int* __restrict__ counts,
                                                  int* __restrict__ offs,
                                                  int* __restrict__ bsum) {
    __shared__ int s[256];
    int t = threadIdx.x;
    int base = blockIdx.x * 1024 + t * 4;
    int v[4];
#pragma unroll
    for (int i = 0; i < 4; ++i) {
        int idx = base + i;
        v[i] = (idx < N_ENT) ? counts[idx] : 0;
    }
    int tot = v[0] + v[1] + v[2] + v[3];
    s[t] = tot;
    for (int off = 1; off < 256; off <<= 1) {
        __syncthreads();
        int x = (t >= off) ? s[t - off] : 0;
        __syncthreads();
        s[t] += x;
    }
    int run = s[t] - tot;
#pragma unroll
    for (int i = 0; i < 4; ++i) {
        if (base + i < N_ENT) offs[base + i] = run;
        run += v[i];
    }
    if (t == 255) bsum[blockIdx.x] = s[255];
}

// ---------------- CSR step 2b: scan the 49 chunk totals ----------------------
__global__ __launch_bounds__(64) void scan_tops(int* __restrict__ bsum) {
    int lane = threadIdx.x;
    int v = (lane < NB_SCAN) ? bsum[lane] : 0;
    int orig = v;
#pragma unroll
    for (int off = 1; off < 64; off <<= 1) {
        int x = __shfl_up(v, off);
        if (lane >= off) v += x;
    }
    if (lane < NB_SCAN) bsum[lane] = v - orig;
}

// ---------------- CSR step 2c: add chunk base, init cursors ------------------
__global__ __launch_bounds__(256) void add_base(int* __restrict__ offs,
                                                int* __restrict__ cursors,
                                                const int* __restrict__ bsum) {
    int t = threadIdx.x;
    int base = blockIdx.x * 1024 + t * 4;
    int b = bsum[blockIdx.x];
#pragma unroll
    for (int i = 0; i < 4; ++i) {
        int idx = base + i;
        if (idx < N_ENT) {
            int o = offs[idx] + b;
            offs[idx] = o;
            cursors[idx] = o;
        }
    }
    if (blockIdx.x == 0 && t == 0) offs[N_ENT] = N_EDG;
}

// ---------------- CSR step 3: fill packed edge payloads (XCD-partitioned) ----
__global__ __launch_bounds__(256) void fill_kernel(const int* __restrict__ head,
                                                   const int* __restrict__ tail,
                                                   const int* __restrict__ etype,
                                                   int* __restrict__ cursors,
                                                   int* __restrict__ packed) {
    int g = blockIdx.x & 7;
    int c = blockIdx.x >> 3;  // 0..124
    int hlo = g * HEADS_PER_GRP;
    int hhi = hlo + HEADS_PER_GRP;
    int base = c * FILL_CHUNK;
    for (int t = threadIdx.x; t < FILL_CHUNK; t += 256) {
        int e = base + t;
        int h = head[e];
        if (h >= hlo && h < hhi) {
            int pos = atomicAdd(&cursors[h], 1);
            packed[pos] = tail[e] | (etype[e] << 20);
        }
    }
}

// ---------------- one-time conversions: x->bf16, weights->bf16, weight copy --
__global__ __launch_bounds__(256) void prep_cvt(const float* __restrict__ emb,
                                                const float* __restrict__ W1,
                                                const float* __restrict__ W2,
                                                const float* __restrict__ wsrc,
                                                unsigned short* __restrict__ xh,
                                                unsigned short* __restrict__ w1bf,
                                                unsigned short* __restrict__ w2bf,
                                                float* __restrict__ wout) {
    long long gid = (long long)blockIdx.x * 256 + threadIdx.x;  // float4 units
    const long long n_x = (long long)N_ENT * CH / 4;   // 1,600,000
    const long long n_w1 = 2 * CH * CH / 4;            // 8,192
    const long long n_w2 = 2 * CH * 2 * CH / 4;        // 16,384
    // total with copyw: 1,625,600 = 6350 * 256 exactly
    if (gid < n_x) {
        long long k = gid * 4;
        float4 v = *(const float4*)&emb[k];
        ushort4 o;
        o.x = f2bf(v.x); o.y = f2bf(v.y); o.z = f2bf(v.z); o.w = f2bf(v.w);
        *(ushort4*)&xh[k] = o;
    } else if (gid < n_x + n_w1) {
        long long k = (gid - n_x) * 4;
        float4 v = *(const float4*)&W1[k];
        ushort4 o;
        o.x = f2bf(v.x); o.y = f2bf(v.y); o.z = f2bf(v.z); o.w = f2bf(v.w);
        *(ushort4*)&w1bf[k] = o;
    } else if (gid < n_x + n_w1 + n_w2) {
        long long k = (gid - n_x - n_w1) * 4;
        float4 v = *(const float4*)&W2[k];
        ushort4 o;
        o.x = f2bf(v.x); o.y = f2bf(v.y); o.z = f2bf(v.z); o.w = f2bf(v.w);
        *(ushort4*)&w2bf[k] = o;
    } else {
        long long k = (gid - n_x - n_w1 - n_w2) * 4;  // < 1024*4
        *(float4*)&wout[k] = *(const float4*)&wsrc[k];
    }
}

// ---------------- aggregate + mean + L2-normalize -----------------------------
// One wave per head row; lane owns channels [2*lane, 2*lane+1].
// Edge metadata scalarized (readfirstlane); gather = base + const voffset.
__global__ __launch_bounds__(512) void agg_kernel(
    const unsigned short* __restrict__ xin, const int* __restrict__ offs,
    const int* __restrict__ packed, const float* __restrict__ rw,
    unsigned short* __restrict__ aggb) {
    __shared__ float ws_[32 * CH];  // rows accessed wave-uniformly -> no conflicts
    int tid = threadIdx.x;
    {
        int base = tid * 8;  // 4096 floats / 512 threads
        *(float4*)&ws_[base] = *(const float4*)&rw[base];
        *(float4*)&ws_[base + 4] = *(const float4*)&rw[base + 4];
    }
    __syncthreads();

    const int w = tid >> 6;
    const int lane = tid & 63;
    const int c2 = lane * 2;
    const int row = blockIdx.x * 8 + w;
    const int beg = __builtin_amdgcn_readfirstlane(offs[row]);
    const int end = __builtin_amdgcn_readfirstlane(offs[row + 1]);

    float2 a0 = {0.f, 0.f}, a1 = {0.f, 0.f}, a2 = {0.f, 0.f}, a3 = {0.f, 0.f};
    int i = beg;
    for (; i + 4 <= end; i += 4) {
        int p0 = __builtin_amdgcn_readfirstlane(packed[i]);
        int p1 = __builtin_amdgcn_readfirstlane(packed[i + 1]);
        int p2 = __builtin_amdgcn_readfirstlane(packed[i + 2]);
        int p3 = __builtin_amdgcn_readfirstlane(packed[i + 3]);
        unsigned v0 = *(const unsigned*)&xin[(long long)(p0 & 0xFFFFF) * CH + c2];
        unsigned v1 = *(const unsigned*)&xin[(long long)(p1 & 0xFFFFF) * CH + c2];
        unsigned v2 = *(const unsigned*)&xin[(long long)(p2 & 0xFFFFF) * CH + c2];
        unsigned v3 = *(const unsigned*)&xin[(long long)(p3 & 0xFFFFF) * CH + c2];
        float2 w0 = *(const float2*)&ws_[((p0 >> 20) << 7) + c2];
        float2 w1 = *(const float2*)&ws_[((p1 >> 20) << 7) + c2];
        float2 w2 = *(const float2*)&ws_[((p2 >> 20) << 7) + c2];
        float2 w3 = *(const float2*)&ws_[((p3 >> 20) << 7) + c2];
        a0.x = fmaf(bflo(v0), w0.x, a0.x); a0.y = fmaf(bfhi(v0), w0.y, a0.y);
        a1.x = fmaf(bflo(v1), w1.x, a1.x); a1.y = fmaf(bfhi(v1), w1.y, a1.y);
        a2.x = fmaf(bflo(v2), w2.x, a2.x); a2.y = fmaf(bfhi(v2), w2.y, a2.y);
        a3.x = fmaf(bflo(v3), w3.x, a3.x); a3.y = fmaf(bfhi(v3), w3.y, a3.y);
    }
    for (; i < end; ++i) {
        int p = __builtin_amdgcn_readfirstlane(packed[i]);
        unsigned v = *(const unsigned*)&xin[(long long)(p & 0xFFFFF) * CH + c2];
        float2 wv = *(const float2*)&ws_[((p >> 20) << 7) + c2];
        a0.x = fmaf(bflo(v), wv.x, a0.x);
        a0.y = fmaf(bfhi(v), wv.y, a0.y);
    }

    float2 acc = {a0.x + a1.x + a2.x + a3.x, a0.y + a1.y + a2.y + a3.y};
    float d = fmaxf((float)(end - beg), 1.f);
    acc.x /= d;
    acc.y /= d;
    float ss = acc.x * acc.x + acc.y * acc.y;
#pragma unroll
    for (int off = 32; off >= 1; off >>= 1) ss += __shfl_xor(ss, off);
    float inv = 1.0f / fmaxf(sqrtf(ss), 1e-12f);
    ushort2 o;
    o.x = f2bf(acc.x * inv);
    o.y = f2bf(acc.y * inv);
    *(ushort2*)&aggb[(long long)row * CH + c2] = o;
}

// ---------------- MFMA dual-GEMM + leaky + add -------------------------------
// out = leaky((x+agg)@W1^T + b1) + leaky(x@W2a^T + agg@W2b^T + b2)
// One 16-row strip per block (grid 3125). A staged via LDS: each of 8 waves
// does ONE coalesced 1KB load + ONE swizzled ds_write_b128 (8KB total), then
// all waves read fragments from LDS. XOR swizzle (chunk^row) on BOTH write and
// read sides -> uniform bank coverage (would be 16-way conflict unswizzled).
// Weight loads issued before the barrier -> overlap staging latency.
__global__ __launch_bounds__(512) void gemm_kernel(
    const unsigned short* __restrict__ xin, const unsigned short* __restrict__ aggb,
    const unsigned short* __restrict__ w1bf, const unsigned short* __restrict__ w2bf,
    const float* __restrict__ b1, const float* __restrict__ b2,
    unsigned short* __restrict__ xout, float* __restrict__ outf) {
    __shared__ __align__(16) unsigned char lds[8192];  // [2][16 rows][256 B]

    const int tid = threadIdx.x;
    const int w = tid >> 6;
    const int lane = tid & 63;
    const int l16 = lane & 15;
    const int lq = lane >> 4;  // 0..3
    const int j = w * 16 + l16;
    const int row0 = blockIdx.x * 16;

    // ---- stage A into LDS (swizzled): wave w<4 stages x, w>=4 stages agg ----
    {
        int half = w >> 2;
        int r = (w & 3) * 4 + lq;   // row 0..15
        int c = l16;                // 16B chunk 0..15 within row
        const unsigned short* src = half ? aggb : xin;
        bf16x8 v = *(const bf16x8*)&src[(long long)(row0 + r) * CH + c * 8];
        *(bf16x8*)&lds[half * 4096 + r * 256 + ((c ^ r) * 16)] = v;
    }

    // ---- weight B-fragments (independent of staging; overlaps latency) ----
    bf16x8 bW1[4], bWa[4], bWb[4];
    const float bb1 = b1[j];
    const float bb2 = b2[j];
#pragma unroll
    for (int kst = 0; kst < 4; ++kst) {
        int kk = kst * 32 + lq * 8;
        bW1[kst] = *(const bf16x8*)&w1bf[j * CH + kk];
        bWa[kst] = *(const bf16x8*)&w2bf[j * 2 * CH + kk];
        bWb[kst] = *(const bf16x8*)&w2bf[j * 2 * CH + CH + kk];
    }
    __syncthreads();

    // ---- fragments from LDS + MFMAs ----
    f32x4 acc1 = {0.f, 0.f, 0.f, 0.f};
    f32x4 acc2 = {0.f, 0.f, 0.f, 0.f};
#pragma unroll
    for (int kst = 0; kst < 4; ++kst) {
        int c = kst * 4 + lq;                       // chunk within row
        int off = l16 * 256 + ((c ^ l16) * 16);     // swizzled
        bf16x8 rh = *(const bf16x8*)&lds[off];
        bf16x8 av = *(const bf16x8*)&lds[4096 + off];
        acc1 = __builtin_amdgcn_mfma_f32_16x16x32_bf16(rh, bW1[kst], acc1, 0, 0, 0);
        acc1 = __builtin_amdgcn_mfma_f32_16x16x32_bf16(av, bW1[kst], acc1, 0, 0, 0);
        acc2 = __builtin_amdgcn_mfma_f32_16x16x32_bf16(rh, bWa[kst], acc2, 0, 0, 0);
        acc2 = __builtin_amdgcn_mfma_f32_16x16x32_bf16(av, bWb[kst], acc2, 0, 0, 0);
    }

#pragma unroll
    for (int r = 0; r < 4; ++r) {
        long long row = row0 + lq * 4 + r;
        float e1 = acc1[r] + bb1;
        e1 = e1 >= 0.f ? e1 : LEAKY * e1;
        float e2 = acc2[r] + bb2;
        e2 = e2 >= 0.f ? e2 : LEAKY * e2;
        float val = e1 + e2;
        if (outf)
            outf[row * CH + j] = val;
        else
            xout[row * CH + j] = f2bf(val);
    }
}

extern "C" void kernel_launch(void* const* d_in, const int* in_sizes, int n_in,
                              void* d_out, int out_size, void* d_ws, size_t ws_size,
                              hipStream_t stream) {
    const float* emb = (const float*)d_in[0];
    const int* eidx = (const int*)d_in[1];   // int inputs arrive as int32
    const int* etype = (const int*)d_in[2];
    const float* weight = (const float*)d_in[3];
    const float* W1w = (const float*)d_in[4];
    const float* W1b = (const float*)d_in[5];
    const float* W2w = (const float*)d_in[6];
    const float* W2b = (const float*)d_in[7];

    float* out = (float*)d_out;
    float* wout = out + (size_t)N_ENT * CH;   // [32][CH]

    // workspace layout (~41.6 MB; proven fits)
    char* ws = (char*)d_ws;
    unsigned short* xh = (unsigned short*)ws;    ws += (size_t)N_ENT * CH * 2;  // 12.8 MB
    unsigned short* xh2 = (unsigned short*)ws;   ws += (size_t)N_ENT * CH * 2;  // 12.8 MB
    unsigned short* aggb = (unsigned short*)ws;  ws += (size_t)N_ENT * CH * 2;  // 12.8 MB
    unsigned short* w1bf = (unsigned short*)ws;  ws += 2 * CH * CH * 2;         // 64 KB
    unsigned short* w2bf = (unsigned short*)ws;  ws += 2 * CH * 2 * CH * 2;     // 128 KB
    int* packed = (int*)ws;                      ws += (size_t)N_EDG * 4;       // 2.4 MB
    int* offs = (int*)ws;                        ws += (size_t)(N_ENT + 1) * 4;
    int* cursors = (int*)ws;                     ws += (size_t)N_ENT * 4;
    int* counts = (int*)ws;                      ws += (size_t)N_ENT * 4;
    int* bsum = (int*)ws;                        ws += 64 * 4;

    const int* head = eidx;
    const int* tail = eidx + N_EDG;

    // ---- one-time prep: CSR + bf16 operand planes (+ weight output copy) ----
    hipMemsetAsync(counts, 0, N_ENT * sizeof(int), stream);
    count_kernel<<<(N_EDG + 255) / 256, 256, 0, stream>>>(head, counts);
    scan_block<<<NB_SCAN, 256, 0, stream>>>(counts, offs, bsum);
    scan_tops<<<1, 64, 0, stream>>>(bsum);
    add_base<<<NB_SCAN, 256, 0, stream>>>(offs, cursors, bsum);
    fill_kernel<<<1000, 256, 0, stream>>>(head, tail, etype, cursors, packed);
    prep_cvt<<<6350, 256, 0, stream>>>(emb, W1w, W2w, weight, xh, w1bf, w2bf, wout);

    // ---- 2 hops, ping-pong: xh -> (aggb) -> xh2 -> (aggb) -> d_out ----
    agg_kernel<<<AGG_BLOCKS, 512, 0, stream>>>(xh, offs, packed, weight, aggb);
    gemm_kernel<<<NSTRIP, 512, 0, stream>>>(
        xh, aggb, w1bf, w2bf, W1b, W2b, xh2, (float*)nullptr);
    agg_kernel<<<AGG_BLOCKS, 512, 0, stream>>>(xh2, offs, packed, weight, aggb);
    gemm_kernel<<<NSTRIP, 512, 0, stream>>>(
        xh2, aggb, w1bf + CH * CH, w2bf + CH * 2 * CH,
        W1b + CH, W2b + CH, (unsigned short*)nullptr, out);
}